// Round 10
// baseline (1299.546 us; speedup 1.0000x reference)
//
#include <hip/hip_runtime.h>

// Problem constants (B,S,F,L) = (512, 1024, 64, 128)
constexpr int Bn = 512;
constexpr int Sn = 1024;
constexpr int Fn = 64;
constexpr int Ln = 128;
constexpr int Gn = 4 * Ln;  // 512 gate rows (i,f,g,o)
constexpr int CH = 16;      // steps per in-kernel x-GEMM chunk
constexpr int NCH = Sn / CH;
constexpr int XST = 44;     // xraw row stride (u32)
constexpr int PST = 1028;   // pre step-stride (floats)
constexpr int HST = 80;     // hsb elem stride (u32)

typedef unsigned int u32;
typedef _Float16 h2 __attribute__((ext_vector_type(2)));
typedef _Float16 h8 __attribute__((ext_vector_type(8)));
typedef float f4 __attribute__((ext_vector_type(4)));

__device__ __forceinline__ float fsig(float v) {
  return __builtin_amdgcn_rcpf(1.0f + __expf(-v));
}
__device__ __forceinline__ h8 as_h8(uint4 v) { return __builtin_bit_cast(h8, v); }

// LGKM-only barrier (r9 fix): __syncthreads emits s_waitcnt vmcnt(0) before
// s_barrier, which (a) force-completes the x global prefetch at chunk barriers
// instead of letting it span the 16 steps, and (b) drains output-store acks at
// every decoder step barrier. Step ordering only needs LDS visibility ->
// lgkmcnt(0) + s_barrier. "memory"-clobber asm on BOTH sides pins compiler
// memory motion (m214 r263 hoisting hazard); register data deps handle vmcnt.
__device__ __forceinline__ void lgkm_barrier() {
  asm volatile("s_waitcnt lgkmcnt(0)" ::: "memory");
  __builtin_amdgcn_s_barrier();
  asm volatile("" ::: "memory");
}

// Pack encoder weights + dense weights to fp16 in workspace.
__global__ void pack_kernel(const float* __restrict__ Wih, const float* __restrict__ Whh,
                            const float* __restrict__ Wd,
                            _Float16* __restrict__ WhE, _Float16* __restrict__ WxE,
                            _Float16* __restrict__ WdH) {
  const int i = blockIdx.x * 256 + threadIdx.x;  // grid covers 65536
  if (i < Gn * Ln) WhE[i] = (_Float16)Whh[i];
  if (i < Gn * Fn) WxE[i] = (_Float16)Wih[i];
  if (i < Fn * Ln) WdH[i] = (_Float16)Wd[i];
}

// Fold decoder dense into the recurrence (fp32 math, fp16 result).
__global__ void combine_dec_kernel(const float* __restrict__ Wih, const float* __restrict__ Whh,
                                   const float* __restrict__ bih, const float* __restrict__ bhh,
                                   const float* __restrict__ Wd, const float* __restrict__ bd,
                                   _Float16* __restrict__ WcH, float* __restrict__ bc) {
  const int t = blockIdx.x;   // gate row 0..511
  const int l = threadIdx.x;  // latent col 0..127
  float s = Whh[t * Ln + l];
#pragma unroll
  for (int j = 0; j < Fn; ++j) s += Wih[t * Fn + j] * Wd[j * Ln + l];
  WcH[t * Ln + l] = (_Float16)s;
  if (l == 0) {
    float sb = bih[t] + bhh[t];
#pragma unroll
    for (int j = 0; j < Fn; ++j) sb += Wih[t * Fn + j] * bd[j];
    bc[t] = sb;
  }
}

// r17 = r15 (M=2 MFMA persistent, 256 blocks x 512 thr, 1 block/CU) + three
// fixes from the r9 issue model (1320 cyc/step = 512 matrix + ~580 VALU +
// ~230 unoverlapped serial tail):
//  (A) lgkm-only step/chunk barriers (see lgkm_barrier above).
//  (B) trans-split activation: every lane group holds DUPLICATE gate regs
//      (C row 4*g16+r repeats with parity r&1 -> reg0/2=elem0, reg1/3=elem1,
//      identical across g16). Lanes 32-63 are free mirrors of 0-31: one sigma
//      instruction covers gate i (low half) and tanh-arg g (high half, arg
//      and result scaled by per-lane consts), a second covers f/o, then two
//      __shfl_xor(.,32) hand (gg,go) to the c-owning low lanes.
//      10 -> 6 trans insts/step, bit-identical math.
//  (C) pre[ss+1] prefetched into regs during step ss (2 b32/lane, low half
//      reads gates i,f; high half g,o) -> activation tail = 2 adds, no LDS.
// NO waves-per-EU cap (r7 lesson). Strides XST/PST/HST per r15 (conflicts
// 9.4e7 -> 1.05e7 verified).
__global__ __launch_bounds__(512)
void rae_mfma4_kernel(const float* __restrict__ x,
                      const _Float16* __restrict__ WhE, const _Float16* __restrict__ WxE,
                      const float* __restrict__ bih_e, const float* __restrict__ bhh_e,
                      const _Float16* __restrict__ WcH, const float* __restrict__ bc,
                      const _Float16* __restrict__ WdH, const float* __restrict__ bd,
                      float* __restrict__ out) {
  const int t = threadIdx.x;
  const int w = t >> 6;    // wave 0..7
  const int l = t & 63;    // lane
  const int jj = l & 15;   // tile column / A-row selector
  const int g16 = l >> 4;  // K-slice group (frag k = g16*8..g16*8+8)
  const bool low = l < 32;
  const int e = g16 & 1;   // elem this lane's activation handles (= partner's)
  const int b = blockIdx.x;

  // activation per-lane constants: high half computes tanh via scaled sigmoid
  const float m1 = low ? 1.0f : 2.0f;    // arg scale & result scale
  const float ad1 = low ? 0.0f : -1.0f;  // g1 = m1*sigma + ad1
  const int gA = low ? 0 : 2, gB = low ? 1 : 3;  // gate tiles for pre fetch

  __shared__ float pre[CH * PST];      // [st][e(514)][col] 65792 B
  __shared__ u32 xraw[2 * CH * XST];   // [e][st][XST u32] 5632 B
  __shared__ u32 hsb[2 * 2 * HST];     // [buf][e][HST u32] 1280 B

  // ---- encoder B-frags: bh[g][kt] = W row (w+8g)*16+jj, halfs kt*32+g16*8 ----
  uint4 bh[4][4];
  float be[4];
#pragma unroll
  for (int g = 0; g < 4; ++g) {
    const int row = (w + 8 * g) * 16 + jj;
#pragma unroll
    for (int kt = 0; kt < 4; ++kt)
      bh[g][kt] = *(const uint4*)(WhE + (size_t)row * 128 + kt * 32 + g16 * 8);
    be[g] = bih_e[row] + bhh_e[row];
  }

  float c = 0.0f;  // cell: lanes 0-15 elem0, 16-31 elem1 (latent w*16+jj)

  for (int i = t; i < 2 * 2 * HST; i += 512) hsb[i] = 0u;  // h = 0 both buffers

  // staging coords: thread -> (elem, step-in-chunk, feature-quad)
  const int se = t >> 8, sst = (t >> 4) & 15, sfq = t & 15;
  const float* xsrc = x + (size_t)b * 2 * Sn * Fn + (size_t)se * Sn * Fn +
                      (size_t)sst * Fn + sfq * 4;
  float4 xv = *(const float4*)xsrc;  // chunk 0 prefetch
  __syncthreads();

  // pre-read offsets (within a step's slab): this lane's 2 gate columns
  const int pofA = e * 514 + (w + 8 * gA) * 16 + jj;
  const int pofB = e * 514 + (w + 8 * gB) * 16 + jj;

  // ================= encoder: 64 chunks x 16 steps =================
  int s = 0;
  for (int ch = 0; ch < NCH; ++ch) {
    {  // write prefetched x chunk fp32->fp16 into xraw (reg dep waits vmcnt)
      h2 p0 = {(_Float16)xv.x, (_Float16)xv.y};
      h2 p1 = {(_Float16)xv.z, (_Float16)xv.w};
      xraw[se * (CH * XST) + sst * XST + sfq * 2] = __builtin_bit_cast(u32, p0);
      xraw[se * (CH * XST) + sst * XST + sfq * 2 + 1] = __builtin_bit_cast(u32, p1);
    }
    lgkm_barrier();
    // ---- chunk GEMM: pre[st][e][col] = x[e,st,:] @ Wx^T[col] + be ----
    {
      uint4 bx0[4], bx1[4];
#pragma unroll
      for (int g = 0; g < 4; ++g) {
        const int row = (w + 8 * g) * 16 + jj;
        bx0[g] = *(const uint4*)(WxE + (size_t)row * 64 + g16 * 8);
        bx1[g] = *(const uint4*)(WxE + (size_t)row * 64 + 32 + g16 * 8);
      }
#pragma unroll
      for (int mt = 0; mt < 2; ++mt) {  // M-tile = elem
        h8 a0 = as_h8(*(const uint4*)&xraw[mt * (CH * XST) + jj * XST + g16 * 4]);
        h8 a1 = as_h8(*(const uint4*)&xraw[mt * (CH * XST) + jj * XST + 16 + g16 * 4]);
#pragma unroll
        for (int g = 0; g < 4; ++g) {
          f4 acc = {be[g], be[g], be[g], be[g]};
          acc = __builtin_amdgcn_mfma_f32_16x16x32_f16(a0, as_h8(bx0[g]), acc, 0, 0, 0);
          acc = __builtin_amdgcn_mfma_f32_16x16x32_f16(a1, as_h8(bx1[g]), acc, 0, 0, 0);
          const int col = (w + 8 * g) * 16 + jj;
#pragma unroll
          for (int r = 0; r < 4; ++r)  // C row = g16*4+r = step-in-chunk
            pre[(g16 * 4 + r) * PST + mt * 514 + col] = acc[r];
        }
      }
    }
    if (ch + 1 < NCH)  // prefetch next chunk; spans the 16 steps (no vmcnt drain)
      xv = *(const float4*)(xsrc + (size_t)(ch + 1) * CH * Fn);
    lgkm_barrier();
    float pA = pre[pofA], pB = pre[pofB];  // step 0 pre values
    // ---- 16 recurrence steps ----
    for (int ss = 0; ss < CH; ++ss, ++s) {
      const int cur = s & 1, nx = cur ^ 1;
      const u32* hb = &hsb[(cur * 2 + (jj & 1)) * HST];  // A row = elem jj&1
      f4 a0 = {0.f, 0.f, 0.f, 0.f}, a1 = a0, a2 = a0, a3 = a0;
#pragma unroll
      for (int kt = 0; kt < 4; ++kt) {
        h8 af = as_h8(*(const uint4*)&hb[kt * 16 + g16 * 4]);
        a0 = __builtin_amdgcn_mfma_f32_16x16x32_f16(af, as_h8(bh[0][kt]), a0, 0, 0, 0);
        a1 = __builtin_amdgcn_mfma_f32_16x16x32_f16(af, as_h8(bh[1][kt]), a1, 0, 0, 0);
        a2 = __builtin_amdgcn_mfma_f32_16x16x32_f16(af, as_h8(bh[2][kt]), a2, 0, 0, 0);
        a3 = __builtin_amdgcn_mfma_f32_16x16x32_f16(af, as_h8(bh[3][kt]), a3, 0, 0, 0);
      }
      // prefetch pre for next step (clamped; ss=15's value unused)
      const int ssn = (ss + 1 < CH) ? ss + 1 : ss;
      const float pAn = pre[ssn * PST + pofA];
      const float pBn = pre[ssn * PST + pofB];
      // trans-split activation (low: i,f + c-own; high: g,o mirror)
      const float sel1 = low ? (e ? a0[1] : a0[0]) : (e ? a2[1] : a2[0]);
      const float sel2 = low ? (e ? a1[1] : a1[0]) : (e ? a3[1] : a3[0]);
      const float g1 = __builtin_fmaf(m1, fsig(m1 * (sel1 + pA)), ad1);  // gi | gg
      const float g2 = fsig(sel2 + pB);                                  // gf | go
      const float gg = __shfl_xor(g1, 32, 64);  // low lanes receive tanh(g)
      const float go = __shfl_xor(g2, 32, 64);  // low lanes receive sigma(o)
      c = __builtin_fmaf(g2, c, g1 * gg);       // low: gf*c + gi*gg
      const float tc = __builtin_fmaf(2.f, fsig(2.f * c), -1.f);
      if (low)
        ((_Float16*)hsb)[(nx * 2 + e) * (2 * HST) + w * 16 + jj] = (_Float16)(go * tc);
      lgkm_barrier();
      pA = pAn; pB = pBn;
    }
  }

  // ================= decoder: 1024 steps =================
  float bdv[4];
#pragma unroll
  for (int g = 0; g < 4; ++g) {  // reload B-frags with folded W_comb
    const int row = (w + 8 * g) * 16 + jj;
#pragma unroll
    for (int kt = 0; kt < 4; ++kt)
      bh[g][kt] = *(const uint4*)(WcH + (size_t)row * 128 + kt * 32 + g16 * 8);
    bdv[g] = bc[row];
  }
  // dense B-frags (waves 0..3 own output tiles 0..3): out feature = w*16+jj
  uint4 dwf[4];
  float dbias = 0.0f;
  const int od = w * 16 + jj;
  if (w < 4) {
#pragma unroll
    for (int kt = 0; kt < 4; ++kt)
      dwf[kt] = *(const uint4*)(WdH + (size_t)od * 128 + kt * 32 + g16 * 8);
    dbias = bd[od];
  }
  float* outb = out + (size_t)b * 2 * Sn * Fn;

  for (int step = 0; step < Sn; ++step, ++s) {
    const int cur = s & 1, nx = cur ^ 1;
    const u32* hb = &hsb[(cur * 2 + (jj & 1)) * HST];
    f4 a0 = {bdv[0], bdv[0], bdv[0], bdv[0]};
    f4 a1 = {bdv[1], bdv[1], bdv[1], bdv[1]};
    f4 a2 = {bdv[2], bdv[2], bdv[2], bdv[2]};
    f4 a3 = {bdv[3], bdv[3], bdv[3], bdv[3]};
#pragma unroll
    for (int kt = 0; kt < 4; ++kt) {
      h8 af = as_h8(*(const uint4*)&hb[kt * 16 + g16 * 4]);
      a0 = __builtin_amdgcn_mfma_f32_16x16x32_f16(af, as_h8(bh[0][kt]), a0, 0, 0, 0);
      a1 = __builtin_amdgcn_mfma_f32_16x16x32_f16(af, as_h8(bh[1][kt]), a1, 0, 0, 0);
      a2 = __builtin_amdgcn_mfma_f32_16x16x32_f16(af, as_h8(bh[2][kt]), a2, 0, 0, 0);
      a3 = __builtin_amdgcn_mfma_f32_16x16x32_f16(af, as_h8(bh[3][kt]), a3, 0, 0, 0);
    }
    // trans-split activation (bias already in acc init)
    const float sel1 = low ? (e ? a0[1] : a0[0]) : (e ? a2[1] : a2[0]);
    const float sel2 = low ? (e ? a1[1] : a1[0]) : (e ? a3[1] : a3[0]);
    const float g1 = __builtin_fmaf(m1, fsig(m1 * sel1), ad1);
    const float g2 = fsig(sel2);
    const float gg = __shfl_xor(g1, 32, 64);
    const float go = __shfl_xor(g2, 32, 64);
    c = __builtin_fmaf(g2, c, g1 * gg);
    const float tc = __builtin_fmaf(2.f, fsig(2.f * c), -1.f);
    if (low)
      ((_Float16*)hsb)[(nx * 2 + e) * (2 * HST) + w * 16 + jj] = (_Float16)(go * tc);
    lgkm_barrier();

    // dense on just-written h (buffer nx): out[2b+e, S-1-step, od].
    // Stores stay outstanding across the next lgkm-only barrier (the win).
    if (w < 4) {
      const u32* hn = &hsb[(nx * 2 + (jj & 1)) * HST];
      f4 d = {0.f, 0.f, 0.f, 0.f};
#pragma unroll
      for (int kt = 0; kt < 4; ++kt) {
        h8 af = as_h8(*(const uint4*)&hn[kt * 16 + g16 * 4]);
        d = __builtin_amdgcn_mfma_f32_16x16x32_f16(af, as_h8(dwf[kt]), d, 0, 0, 0);
      }
      if (l < 16) {
        const size_t roff = (size_t)(Sn - 1 - step) * Fn + w * 16 + l;
        outb[roff] = d[0] + dbias;                    // elem 0 (C row 0)
        outb[(size_t)Sn * Fn + roff] = d[1] + dbias;  // elem 1 (C row 1)
      }
    }
  }
}

extern "C" void kernel_launch(void* const* d_in, const int* in_sizes, int n_in,
                              void* d_out, int out_size, void* d_ws, size_t ws_size,
                              hipStream_t stream) {
  const float* x     = (const float*)d_in[0];
  const float* Wih_e = (const float*)d_in[1];
  const float* Whh_e = (const float*)d_in[2];
  const float* bih_e = (const float*)d_in[3];
  const float* bhh_e = (const float*)d_in[4];
  const float* Wih_d = (const float*)d_in[5];
  const float* Whh_d = (const float*)d_in[6];
  const float* bih_d = (const float*)d_in[7];
  const float* bhh_d = (const float*)d_in[8];
  const float* Wd    = (const float*)d_in[9];
  const float* bd    = (const float*)d_in[10];
  float* out = (float*)d_out;

  // workspace: only the fixed fp16 weight copies + combined bias (~350 KB)
  _Float16* WhE = (_Float16*)d_ws;           // 512*128
  _Float16* WxE = WhE + Gn * Ln;             // 512*64
  _Float16* WcH = WxE + Gn * Fn;             // 512*128
  _Float16* WdH = WcH + Gn * Ln;             // 64*128
  float* bc = (float*)(WdH + Fn * Ln);       // 512

  pack_kernel<<<256, 256, 0, stream>>>(Wih_e, Whh_e, Wd, WhE, WxE, WdH);
  combine_dec_kernel<<<Gn, Ln, 0, stream>>>(Wih_d, Whh_d, bih_d, bhh_d, Wd, bd, WcH, bc);
  rae_mfma4_kernel<<<Bn / 2, 512, 0, stream>>>(x, WhE, WxE, bih_e, bhh_e,
                                               WcH, bc, WdH, bd, out);
}